// Round 14
// baseline (254.850 us; speedup 1.0000x reference)
//
#include <hip/hip_runtime.h>

#define F_IN 128
#define HID  64
#define NCLS 16

#define BSHIFT 8            // 256 nodes per bucket
#define BNODES 256
#define NB_MAX 512          // max buckets (N<=128k)
#define CHUNK  8192         // edges per partition block (nchunks must be <=256 for col_scan)
#define CAP    8192         // max edges per bucket in LDS (mean 4352, 50+ sigma margin)

typedef __attribute__((ext_vector_type(8))) short bf16x8;
typedef __attribute__((ext_vector_type(4))) float f32x4;

// round-to-nearest-even fp32 -> bf16
__device__ __forceinline__ unsigned short f2bf(float f) {
    unsigned int u = __float_as_uint(f);
    u += 0x7FFFu + ((u >> 16) & 1u);
    return (unsigned short)(u >> 16);
}
__device__ __forceinline__ float bf2f(unsigned short h) {
    return __uint_as_float((unsigned int)h << 16);
}
__device__ __forceinline__ float bflo(unsigned int u) {
    return __uint_as_float(u << 16);
}
__device__ __forceinline__ float bfhi(unsigned int u) {
    return __uint_as_float(u & 0xFFFF0000u);
}

// ---------- pass 1: per-block bucket histogram (non-atomic global) + fused w1t ----------
__global__ __launch_bounds__(256) void hist_w1t_kernel(const int* __restrict__ dst,
                                                       int* __restrict__ blk_hist,
                                                       const float* __restrict__ W1,
                                                       unsigned short* __restrict__ w1t,
                                                       int E, int NB, int nchunks) {
    int blk = blockIdx.x;
    int tid = threadIdx.x;
    if (blk == nchunks) {           // fused W1 -> bf16 transpose block
        for (int i = tid; i < F_IN * HID; i += 256) {
            int k = i >> 6, n = i & 63;
            w1t[n * F_IN + k] = f2bf(W1[i]);
        }
        return;
    }
    __shared__ int hist[NB_MAX];
    for (int i = tid; i < NB; i += 256) hist[i] = 0;
    __syncthreads();
    int cb = blk * CHUNK;
    #pragma unroll
    for (int k = 0; k < CHUNK / 1024; k++) {
        int e = cb + (k * 256 + tid) * 4;
        if (e + 3 < E) {
            int4 d4 = *(const int4*)&dst[e];
            atomicAdd(&hist[d4.x >> BSHIFT], 1);
            atomicAdd(&hist[d4.y >> BSHIFT], 1);
            atomicAdd(&hist[d4.z >> BSHIFT], 1);
            atomicAdd(&hist[d4.w >> BSHIFT], 1);
        } else {
            for (int t = 0; t < 4; t++)
                if (e + t < E) atomicAdd(&hist[dst[e + t] >> BSHIFT], 1);
        }
    }
    __syncthreads();
    for (int i = tid; i < NB; i += 256) blk_hist[(size_t)blk * NB + i] = hist[i];
}

// ---------- pass 2a: parallel column reduce -> bucket totals ----------
__global__ __launch_bounds__(256) void col_reduce(const int* __restrict__ blk_hist,
                                                  int* __restrict__ bucket_count,
                                                  int NB, int nchunks) {
    __shared__ int red[256];
    int b = blockIdx.x;
    int tid = threadIdx.x;
    int s = 0;
    for (int j = tid; j < nchunks; j += 256) s += blk_hist[(size_t)j * NB + b];
    red[tid] = s;
    __syncthreads();
    for (int off = 128; off > 0; off >>= 1) {
        if (tid < off) red[tid] += red[tid + off];
        __syncthreads();
    }
    if (tid == 0) bucket_count[b] = red[0];
}

// ---------- pass 2b: single-block scan of bucket totals -> bases ----------
__global__ __launch_bounds__(512) void scan_small(const int* __restrict__ bucket_count,
                                                  int* __restrict__ bucket_base,
                                                  int* __restrict__ row_ptr,
                                                  int NB, int N, int E) {
    __shared__ int s[512];
    int tid = threadIdx.x;
    int v = (tid < NB) ? bucket_count[tid] : 0;
    s[tid] = v;
    __syncthreads();
    for (int off = 1; off < 512; off <<= 1) {
        int t = (tid >= off) ? s[tid - off] : 0;
        __syncthreads();
        s[tid] += t;
        __syncthreads();
    }
    if (tid < NB) bucket_base[tid] = s[tid] - v;
    if (tid == 0) { bucket_base[NB] = E; row_ptr[N] = E; }
}

// ---------- pass 2c: per-bucket parallel column scan -> absolute per-chunk bases ----------
__global__ __launch_bounds__(256) void col_scan(int* __restrict__ blk_hist,
                                                const int* __restrict__ bucket_base,
                                                int NB, int nchunks) {
    __shared__ int s[256];
    int b = blockIdx.x;
    int tid = threadIdx.x;
    int v = (tid < nchunks) ? blk_hist[(size_t)tid * NB + b] : 0;
    s[tid] = v;
    __syncthreads();
    for (int off = 1; off < 256; off <<= 1) {
        int t = (tid >= off) ? s[tid - off] : 0;
        __syncthreads();
        s[tid] += t;
        __syncthreads();
    }
    if (tid < nchunks) blk_hist[(size_t)tid * NB + b] = s[tid] - v + bucket_base[b];
}

// ---------- pass 3: partition via LDS counting sort, run-coalesced writeout ----------
__global__ __launch_bounds__(512) void scatter_kernel(const int* __restrict__ src,
                                                      const int* __restrict__ dst,
                                                      const int* __restrict__ blk_hist,
                                                      unsigned int* __restrict__ part,
                                                      int E, int NB) {
    __shared__ unsigned int ordered[CHUNK];      // 32 KB, bucket-grouped edges
    __shared__ unsigned short bkt[CHUNK];        // 16 KB, bucket id per slot
    __shared__ int hist[NB_MAX];                 // counter, then cursor
    __shared__ int scanb[NB_MAX];
    __shared__ int lexcl[NB_MAX];                // local exclusive base
    __shared__ int gbase[NB_MAX];                // absolute global base for this chunk
    int tid = threadIdx.x;
    int blk = blockIdx.x;
    int cb = blk * CHUNK;
    int valid = min(CHUNK, E - cb);

    for (int i = tid; i < NB; i += 512) {
        hist[i] = 0;
        gbase[i] = blk_hist[(size_t)blk * NB + i];
    }
    __syncthreads();
    // local histogram
    #pragma unroll
    for (int k = 0; k < CHUNK / 2048; k++) {
        int e4 = (k * 512 + tid) * 4;
        int e = cb + e4;
        if (e4 + 3 < valid) {
            int4 d4 = *(const int4*)&dst[e];
            atomicAdd(&hist[d4.x >> BSHIFT], 1);
            atomicAdd(&hist[d4.y >> BSHIFT], 1);
            atomicAdd(&hist[d4.z >> BSHIFT], 1);
            atomicAdd(&hist[d4.w >> BSHIFT], 1);
        } else {
            for (int t = 0; t < 4; t++)
                if (e4 + t < valid) atomicAdd(&hist[dst[e + t] >> BSHIFT], 1);
        }
    }
    __syncthreads();
    // exclusive scan of local hist
    int v = (tid < NB) ? hist[tid] : 0;
    scanb[tid] = v;
    __syncthreads();
    for (int off = 1; off < 512; off <<= 1) {
        int t = (tid >= off) ? scanb[tid - off] : 0;
        __syncthreads();
        scanb[tid] += t;
        __syncthreads();
    }
    if (tid < NB) {
        int ex = scanb[tid] - v;
        lexcl[tid] = ex;
        hist[tid] = ex;      // reuse as cursor
    }
    __syncthreads();
    // counting-sort into LDS (bucket-grouped)
    #pragma unroll
    for (int k = 0; k < CHUNK / 2048; k++) {
        int e4 = (k * 512 + tid) * 4;
        int e = cb + e4;
        if (e4 + 3 < valid) {
            int4 d4 = *(const int4*)&dst[e];
            int4 s4 = *(const int4*)&src[e];
            int b0 = d4.x >> BSHIFT; int p0 = atomicAdd(&hist[b0], 1);
            ordered[p0] = ((unsigned int)(d4.x & (BNODES - 1)) << 24) | (unsigned int)s4.x;
            bkt[p0] = (unsigned short)b0;
            int b1 = d4.y >> BSHIFT; int p1 = atomicAdd(&hist[b1], 1);
            ordered[p1] = ((unsigned int)(d4.y & (BNODES - 1)) << 24) | (unsigned int)s4.y;
            bkt[p1] = (unsigned short)b1;
            int b2 = d4.z >> BSHIFT; int p2 = atomicAdd(&hist[b2], 1);
            ordered[p2] = ((unsigned int)(d4.z & (BNODES - 1)) << 24) | (unsigned int)s4.z;
            bkt[p2] = (unsigned short)b2;
            int b3 = d4.w >> BSHIFT; int p3 = atomicAdd(&hist[b3], 1);
            ordered[p3] = ((unsigned int)(d4.w & (BNODES - 1)) << 24) | (unsigned int)s4.w;
            bkt[p3] = (unsigned short)b3;
        } else {
            for (int t = 0; t < 4; t++)
                if (e4 + t < valid) {
                    int d = dst[e + t];
                    int b = d >> BSHIFT;
                    int pos = atomicAdd(&hist[b], 1);
                    ordered[pos] = ((unsigned int)(d & (BNODES - 1)) << 24) | (unsigned int)src[e + t];
                    bkt[pos] = (unsigned short)b;
                }
        }
    }
    __syncthreads();
    // run-coalesced writeout: consecutive i within a bucket-run -> consecutive addrs
    for (int i = tid; i < valid; i += 512) {
        int b = bkt[i];
        part[gbase[b] + (i - lexcl[b])] = ordered[i];
    }
}

// ---------- pass 4: per-bucket counting sort -> csr_src, row_ptr, dis ----------
__global__ __launch_bounds__(256) void csr_build(const unsigned int* __restrict__ part,
                                                 const int* __restrict__ bucket_base,
                                                 int* __restrict__ csr_src,
                                                 int* __restrict__ row_ptr,
                                                 float* __restrict__ dis,
                                                 int N) {
    __shared__ unsigned int eL[CAP];
    __shared__ unsigned int outL[CAP];
    __shared__ int cnt[BNODES];
    __shared__ int sc[BNODES];
    __shared__ int cur[BNODES];
    int tid = threadIdx.x;
    int b = blockIdx.x;
    int eB = bucket_base[b];
    int eN = bucket_base[b + 1] - eB;
    if (eN > CAP) eN = CAP;

    cnt[tid] = 0;
    __syncthreads();
    for (int i = tid; i < eN; i += 256) {
        unsigned int v = part[eB + i];
        eL[i] = v;
        atomicAdd(&cnt[v >> 24], 1);
    }
    __syncthreads();
    int myc = cnt[tid];
    sc[tid] = myc;
    __syncthreads();
    for (int off = 1; off < 256; off <<= 1) {
        int t = (tid >= off) ? sc[tid - off] : 0;
        __syncthreads();
        sc[tid] += t;
        __syncthreads();
    }
    int excl = sc[tid] - myc;
    cur[tid] = excl;
    int gnode = b * BNODES + tid;
    if (gnode < N) {
        row_ptr[gnode] = eB + excl;
        float d = (float)myc;
        dis[gnode] = d > 0.0f ? rsqrtf(fmaxf(d, 1.0f)) : 0.0f;
    }
    __syncthreads();
    for (int i = tid; i < eN; i += 256) {
        unsigned int v = eL[i];
        int pos = atomicAdd(&cur[v >> 24], 1);
        outL[pos] = v & 0xFFFFFFu;
    }
    __syncthreads();
    for (int i = tid; i < eN; i += 256)
        csr_src[eB + i] = (int)outL[i];
}

// ---------- gemm1 via MFMA bf16: 64 rows/block, 4 waves x (16 rows x 64 cols) ----------
__global__ __launch_bounds__(256) void gemm1_kernel(
        const float* __restrict__ x, const unsigned short* __restrict__ w1t,
        const float* __restrict__ dis, unsigned short* __restrict__ h1b, int N) {
    __shared__ unsigned short xs[64][136];
    __shared__ unsigned short wsb[64][136];
    __shared__ float diss[64];
    int tid = threadIdx.x;
    int w = tid >> 6;
    int lane = tid & 63;
    int row0 = blockIdx.x * 64;

    #pragma unroll
    for (int it = 0; it < 8; it++) {
        int f = it * 256 + tid;
        int r = f >> 5, c = f & 31;
        float4 v = make_float4(0.f, 0.f, 0.f, 0.f);
        if (row0 + r < N) v = ((const float4*)x)[(size_t)(row0 + r) * 32 + c];
        unsigned int p0 = (unsigned int)f2bf(v.x) | ((unsigned int)f2bf(v.y) << 16);
        unsigned int p1 = (unsigned int)f2bf(v.z) | ((unsigned int)f2bf(v.w) << 16);
        *(uint2*)&xs[r][c * 4] = make_uint2(p0, p1);
    }
    #pragma unroll
    for (int it = 0; it < 4; it++) {
        int f = it * 256 + tid;
        int r = f >> 4, c = f & 15;
        *(uint4*)&wsb[r][c * 8] = ((const uint4*)w1t)[f];
    }
    if (tid < 64) diss[tid] = (row0 + tid < N) ? dis[row0 + tid] : 0.f;
    __syncthreads();

    int q = lane >> 4;
    int l15 = lane & 15;
    f32x4 acc[4] = {{0,0,0,0},{0,0,0,0},{0,0,0,0},{0,0,0,0}};
    bf16x8 a[4];
    #pragma unroll
    for (int kk = 0; kk < 4; kk++)
        a[kk] = *(const bf16x8*)&xs[w * 16 + l15][kk * 32 + q * 8];
    #pragma unroll
    for (int kk = 0; kk < 4; kk++) {
        #pragma unroll
        for (int ct = 0; ct < 4; ct++) {
            bf16x8 b = *(const bf16x8*)&wsb[ct * 16 + l15][kk * 32 + q * 8];
            acc[ct] = __builtin_amdgcn_mfma_f32_16x16x32_bf16(a[kk], b, acc[ct], 0, 0, 0);
        }
    }
    __syncthreads();
    #pragma unroll
    for (int ct = 0; ct < 4; ct++) {
        #pragma unroll
        for (int r = 0; r < 4; r++) {
            int m = w * 16 + q * 4 + r;
            xs[m][ct * 16 + l15] = f2bf(acc[ct][r] * diss[m]);
        }
    }
    __syncthreads();
    #pragma unroll
    for (int it = 0; it < 2; it++) {
        int f = it * 256 + tid;
        int r = f >> 3, c = f & 7;
        if (row0 + r < N)
            ((uint4*)&h1b[(size_t)(row0 + r) * HID])[c] = *(const uint4*)&xs[r][c * 8];
    }
}

// ---------- fused layer-1 agg + ReLU + W2 GEMM ----------
__global__ __launch_bounds__(256) void agg1_fused(
        const int* __restrict__ row_ptr, const int* __restrict__ csr_src,
        const unsigned short* __restrict__ h1b, const float* __restrict__ dis,
        const float* __restrict__ b1, const float* __restrict__ W2,
        unsigned short* __restrict__ h2b, int N) {
    __shared__ float W2s[HID][NCLS + 1];
    __shared__ float ts[4][HID];
    int tid = threadIdx.x;
    for (int i = tid; i < HID * NCLS; i += 256) W2s[i >> 4][i & 15] = W2[i];
    __syncthreads();

    int w = tid >> 6;
    int lane = tid & 63;
    int n = blockIdx.x * 4 + w;
    int slot = lane >> 4;
    int p = lane & 15;

    float a0 = 0.f, a1 = 0.f, a2 = 0.f, a3 = 0.f;
    float dn = 0.f;
    if (n < N) {
        dn = dis[n];
        int beg = row_ptr[n];
        int end = row_ptr[n + 1];
        int i = beg + slot;
        for (; i + 12 < end; i += 16) {
            int s0 = csr_src[i];
            int s1 = csr_src[i + 4];
            int s2 = csr_src[i + 8];
            int s3 = csr_src[i + 12];
            uint2 v0 = *(const uint2*)&h1b[(size_t)s0 * HID + p * 4];
            uint2 v1 = *(const uint2*)&h1b[(size_t)s1 * HID + p * 4];
            uint2 v2 = *(const uint2*)&h1b[(size_t)s2 * HID + p * 4];
            uint2 v3 = *(const uint2*)&h1b[(size_t)s3 * HID + p * 4];
            a0 += (bflo(v0.x) + bflo(v1.x)) + (bflo(v2.x) + bflo(v3.x));
            a1 += (bfhi(v0.x) + bfhi(v1.x)) + (bfhi(v2.x) + bfhi(v3.x));
            a2 += (bflo(v0.y) + bflo(v1.y)) + (bflo(v2.y) + bflo(v3.y));
            a3 += (bfhi(v0.y) + bfhi(v1.y)) + (bfhi(v2.y) + bfhi(v3.y));
        }
        for (; i < end; i += 4) {
            int s = csr_src[i];
            uint2 v = *(const uint2*)&h1b[(size_t)s * HID + p * 4];
            a0 += bflo(v.x);
            a1 += bfhi(v.x);
            a2 += bflo(v.y);
            a3 += bfhi(v.y);
        }
    }
    a0 += __shfl_xor(a0, 16, 64); a0 += __shfl_xor(a0, 32, 64);
    a1 += __shfl_xor(a1, 16, 64); a1 += __shfl_xor(a1, 32, 64);
    a2 += __shfl_xor(a2, 16, 64); a2 += __shfl_xor(a2, 32, 64);
    a3 += __shfl_xor(a3, 16, 64); a3 += __shfl_xor(a3, 32, 64);

    if (n < N && slot == 0) {
        ts[w][p * 4 + 0] = fmaxf(dn * a0 + b1[p * 4 + 0], 0.f);
        ts[w][p * 4 + 1] = fmaxf(dn * a1 + b1[p * 4 + 1], 0.f);
        ts[w][p * 4 + 2] = fmaxf(dn * a2 + b1[p * 4 + 2], 0.f);
        ts[w][p * 4 + 3] = fmaxf(dn * a3 + b1[p * 4 + 3], 0.f);
    }
    int q = lane >> 4;
    int c = lane & 15;
    float pacc = 0.f;
    #pragma unroll
    for (int jj = 0; jj < 16; jj++) {
        int j = q * 16 + jj;
        pacc += ts[w][j] * W2s[j][c];
    }
    pacc += __shfl_xor(pacc, 16, 64);
    pacc += __shfl_xor(pacc, 32, 64);
    if (n < N && q == 0) h2b[(size_t)n * NCLS + c] = f2bf(pacc * dn);
}

// ---------- fused layer-2 agg + epilogue ----------
__global__ __launch_bounds__(256) void agg2_fused(
        const int* __restrict__ row_ptr, const int* __restrict__ csr_src,
        const unsigned short* __restrict__ h2b, const float* __restrict__ dis,
        const float* __restrict__ b2, float* __restrict__ out, int N) {
    int tid = blockIdx.x * blockDim.x + threadIdx.x;
    int n = tid >> 6;
    int lane = tid & 63;
    if (n >= N) return;
    int slot = lane >> 2;
    int p = lane & 3;

    float a0 = 0.f, a1 = 0.f, a2 = 0.f, a3 = 0.f;
    int beg = row_ptr[n];
    int end = row_ptr[n + 1];
    for (int i = beg + slot; i < end; i += 16) {
        int s = csr_src[i];
        uint2 v = *(const uint2*)&h2b[(size_t)s * NCLS + p * 4];
        a0 += bflo(v.x);
        a1 += bfhi(v.x);
        a2 += bflo(v.y);
        a3 += bfhi(v.y);
    }
    #pragma unroll
    for (int m = 4; m <= 32; m <<= 1) {
        a0 += __shfl_xor(a0, m, 64);
        a1 += __shfl_xor(a1, m, 64);
        a2 += __shfl_xor(a2, m, 64);
        a3 += __shfl_xor(a3, m, 64);
    }
    if (lane < 4) {
        float dn = dis[n];
        float4 o = make_float4(dn * a0 + b2[p * 4 + 0], dn * a1 + b2[p * 4 + 1],
                               dn * a2 + b2[p * 4 + 2], dn * a3 + b2[p * 4 + 3]);
        *(float4*)&out[(size_t)n * NCLS + p * 4] = o;
    }
}

extern "C" void kernel_launch(void* const* d_in, const int* in_sizes, int n_in,
                              void* d_out, int out_size, void* d_ws, size_t ws_size,
                              hipStream_t stream) {
    const float* x   = (const float*)d_in[0];
    const int*   src = (const int*)  d_in[1];
    const int*   dst = (const int*)  d_in[2];
    const float* W1  = (const float*)d_in[3];
    const float* b1  = (const float*)d_in[4];
    const float* W2  = (const float*)d_in[5];
    const float* b2  = (const float*)d_in[6];
    float* out = (float*)d_out;
    int E = in_sizes[1];
    int N = in_sizes[0] / F_IN;
    int NB = (N + BNODES - 1) >> BSHIFT;
    int nchunks = (E + CHUNK - 1) / CHUNK;   // 208 for E=1.7M (col_scan requires <=256)

    char* ws = (char*)d_ws;
    size_t off = 0;
    auto alloc = [&](size_t bytes) { size_t o = off; off = (off + bytes + 255) & ~(size_t)255; return (void*)(ws + o); };
    int*   bucket_count  = (int*)  alloc((size_t)NB * 4);
    int*   bucket_base   = (int*)  alloc((size_t)(NB + 1) * 4);
    int*   blk_hist      = (int*)  alloc((size_t)nchunks * NB * 4);
    int*   row_ptr       = (int*)  alloc((size_t)(N + 1) * 4);
    int*   csr_src       = (int*)  alloc((size_t)E * 4);
    float* dis           = (float*)alloc((size_t)N * 4);
    unsigned short* w1t  = (unsigned short*)alloc((size_t)F_IN * HID * 2);
    unsigned short* h1b  = (unsigned short*)alloc((size_t)N * HID * 2);
    unsigned short* h2b  = (unsigned short*)alloc((size_t)N * NCLS * 2);
    // part[] aliases h1b: dead before gemm1 writes h1b (E*4 = 6.8MB <= N*HID*2 = 12.8MB)
    unsigned int* part   = (unsigned int*)h1b;

    hist_w1t_kernel<<<nchunks + 1, 256, 0, stream>>>(dst, blk_hist, W1, w1t, E, NB, nchunks);
    col_reduce     <<<NB, 256, 0, stream>>>(blk_hist, bucket_count, NB, nchunks);
    scan_small     <<<1, 512, 0, stream>>>(bucket_count, bucket_base, row_ptr, NB, N, E);
    col_scan       <<<NB, 256, 0, stream>>>(blk_hist, bucket_base, NB, nchunks);
    scatter_kernel <<<nchunks, 512, 0, stream>>>(src, dst, blk_hist, part, E, NB);
    csr_build      <<<NB, 256, 0, stream>>>(part, bucket_base, csr_src, row_ptr, dis, N);
    gemm1_kernel   <<<(N + 63) / 64, 256, 0, stream>>>(x, w1t, dis, h1b, N);
    agg1_fused     <<<(N + 3) / 4, 256, 0, stream>>>(row_ptr, csr_src, h1b, dis, b1, W2, h2b, N);
    agg2_fused     <<<(N + 3) / 4, 256, 0, stream>>>(row_ptr, csr_src, h2b, dis, b2, out, N);
}

// Round 15
// 227.289 us; speedup vs baseline: 1.1213x; 1.1213x over previous
//
#include <hip/hip_runtime.h>

#define F_IN 128
#define HID  64
#define NCLS 16

#define BSHIFT 8            // 256 nodes per bucket
#define BNODES 256
#define NB_MAX 512          // max buckets (N<=128k)
#define CHUNK  8192         // edges per partition block (nchunks must be <=256 for col_scan)
#define CAP    8192         // max edges per bucket in LDS (mean 4352, 50+ sigma margin)

typedef __attribute__((ext_vector_type(8))) short bf16x8;
typedef __attribute__((ext_vector_type(4))) float f32x4;

// round-to-nearest-even fp32 -> bf16
__device__ __forceinline__ unsigned short f2bf(float f) {
    unsigned int u = __float_as_uint(f);
    u += 0x7FFFu + ((u >> 16) & 1u);
    return (unsigned short)(u >> 16);
}
__device__ __forceinline__ float bf2f(unsigned short h) {
    return __uint_as_float((unsigned int)h << 16);
}
__device__ __forceinline__ float bflo(unsigned int u) {
    return __uint_as_float(u << 16);
}
__device__ __forceinline__ float bfhi(unsigned int u) {
    return __uint_as_float(u & 0xFFFF0000u);
}

// ---------- pass 1: per-block bucket histogram (non-atomic global) + fused w1t ----------
__global__ __launch_bounds__(256) void hist_w1t_kernel(const int* __restrict__ dst,
                                                       int* __restrict__ blk_hist,
                                                       const float* __restrict__ W1,
                                                       unsigned short* __restrict__ w1t,
                                                       int E, int NB, int nchunks) {
    int blk = blockIdx.x;
    int tid = threadIdx.x;
    if (blk == nchunks) {           // fused W1 -> bf16 transpose block
        for (int i = tid; i < F_IN * HID; i += 256) {
            int k = i >> 6, n = i & 63;
            w1t[n * F_IN + k] = f2bf(W1[i]);
        }
        return;
    }
    __shared__ int hist[NB_MAX];
    for (int i = tid; i < NB; i += 256) hist[i] = 0;
    __syncthreads();
    int cb = blk * CHUNK;
    #pragma unroll
    for (int k = 0; k < CHUNK / 1024; k++) {
        int e = cb + (k * 256 + tid) * 4;
        if (e + 3 < E) {
            int4 d4 = *(const int4*)&dst[e];
            atomicAdd(&hist[d4.x >> BSHIFT], 1);
            atomicAdd(&hist[d4.y >> BSHIFT], 1);
            atomicAdd(&hist[d4.z >> BSHIFT], 1);
            atomicAdd(&hist[d4.w >> BSHIFT], 1);
        } else {
            for (int t = 0; t < 4; t++)
                if (e + t < E) atomicAdd(&hist[dst[e + t] >> BSHIFT], 1);
        }
    }
    __syncthreads();
    for (int i = tid; i < NB; i += 256) blk_hist[(size_t)blk * NB + i] = hist[i];
}

// ---------- pass 2a: parallel column reduce -> bucket totals ----------
__global__ __launch_bounds__(256) void col_reduce(const int* __restrict__ blk_hist,
                                                  int* __restrict__ bucket_count,
                                                  int NB, int nchunks) {
    __shared__ int red[256];
    int b = blockIdx.x;
    int tid = threadIdx.x;
    int s = 0;
    for (int j = tid; j < nchunks; j += 256) s += blk_hist[(size_t)j * NB + b];
    red[tid] = s;
    __syncthreads();
    for (int off = 128; off > 0; off >>= 1) {
        if (tid < off) red[tid] += red[tid + off];
        __syncthreads();
    }
    if (tid == 0) bucket_count[b] = red[0];
}

// ---------- pass 2b: single-block scan of bucket totals -> bases ----------
__global__ __launch_bounds__(512) void scan_small(const int* __restrict__ bucket_count,
                                                  int* __restrict__ bucket_base,
                                                  int* __restrict__ row_ptr,
                                                  int NB, int N, int E) {
    __shared__ int s[512];
    int tid = threadIdx.x;
    int v = (tid < NB) ? bucket_count[tid] : 0;
    s[tid] = v;
    __syncthreads();
    for (int off = 1; off < 512; off <<= 1) {
        int t = (tid >= off) ? s[tid - off] : 0;
        __syncthreads();
        s[tid] += t;
        __syncthreads();
    }
    if (tid < NB) bucket_base[tid] = s[tid] - v;
    if (tid == 0) { bucket_base[NB] = E; row_ptr[N] = E; }
}

// ---------- pass 2c: per-bucket parallel column scan -> absolute per-chunk bases ----------
__global__ __launch_bounds__(256) void col_scan(int* __restrict__ blk_hist,
                                                const int* __restrict__ bucket_base,
                                                int NB, int nchunks) {
    __shared__ int s[256];
    int b = blockIdx.x;
    int tid = threadIdx.x;
    int v = (tid < nchunks) ? blk_hist[(size_t)tid * NB + b] : 0;
    s[tid] = v;
    __syncthreads();
    for (int off = 1; off < 256; off <<= 1) {
        int t = (tid >= off) ? s[tid - off] : 0;
        __syncthreads();
        s[tid] += t;
        __syncthreads();
    }
    if (tid < nchunks) blk_hist[(size_t)tid * NB + b] = s[tid] - v + bucket_base[b];
}

// ---------- pass 3: single-pass partition (R13 version — no global atomics) ----------
__global__ __launch_bounds__(256) void scatter_kernel(const int* __restrict__ src,
                                                      const int* __restrict__ dst,
                                                      const int* __restrict__ blk_hist,
                                                      unsigned int* __restrict__ part,
                                                      int E, int NB) {
    __shared__ int cur[NB_MAX];
    int tid = threadIdx.x;
    int blk = blockIdx.x;
    for (int i = tid; i < NB; i += 256) cur[i] = blk_hist[(size_t)blk * NB + i];
    __syncthreads();
    int cb = blk * CHUNK;
    #pragma unroll
    for (int k = 0; k < CHUNK / 1024; k++) {
        int e = cb + (k * 256 + tid) * 4;
        if (e + 3 < E) {
            int4 d4 = *(const int4*)&dst[e];
            int4 s4 = *(const int4*)&src[e];
            int p0 = atomicAdd(&cur[d4.x >> BSHIFT], 1);
            part[p0] = ((unsigned int)(d4.x & (BNODES - 1)) << 24) | (unsigned int)s4.x;
            int p1 = atomicAdd(&cur[d4.y >> BSHIFT], 1);
            part[p1] = ((unsigned int)(d4.y & (BNODES - 1)) << 24) | (unsigned int)s4.y;
            int p2 = atomicAdd(&cur[d4.z >> BSHIFT], 1);
            part[p2] = ((unsigned int)(d4.z & (BNODES - 1)) << 24) | (unsigned int)s4.z;
            int p3 = atomicAdd(&cur[d4.w >> BSHIFT], 1);
            part[p3] = ((unsigned int)(d4.w & (BNODES - 1)) << 24) | (unsigned int)s4.w;
        } else {
            for (int t = 0; t < 4; t++)
                if (e + t < E) {
                    int d = dst[e + t];
                    int pos = atomicAdd(&cur[d >> BSHIFT], 1);
                    part[pos] = ((unsigned int)(d & (BNODES - 1)) << 24) | (unsigned int)src[e + t];
                }
        }
    }
}

// ---------- pass 4: per-bucket counting sort -> csr_src, row_ptr, dis ----------
__global__ __launch_bounds__(256) void csr_build(const unsigned int* __restrict__ part,
                                                 const int* __restrict__ bucket_base,
                                                 int* __restrict__ csr_src,
                                                 int* __restrict__ row_ptr,
                                                 float* __restrict__ dis,
                                                 int N) {
    __shared__ unsigned int eL[CAP];
    __shared__ unsigned int outL[CAP];
    __shared__ int cnt[BNODES];
    __shared__ int sc[BNODES];
    __shared__ int cur[BNODES];
    int tid = threadIdx.x;
    int b = blockIdx.x;
    int eB = bucket_base[b];
    int eN = bucket_base[b + 1] - eB;
    if (eN > CAP) eN = CAP;

    cnt[tid] = 0;
    __syncthreads();
    for (int i = tid; i < eN; i += 256) {
        unsigned int v = part[eB + i];
        eL[i] = v;
        atomicAdd(&cnt[v >> 24], 1);
    }
    __syncthreads();
    int myc = cnt[tid];
    sc[tid] = myc;
    __syncthreads();
    for (int off = 1; off < 256; off <<= 1) {
        int t = (tid >= off) ? sc[tid - off] : 0;
        __syncthreads();
        sc[tid] += t;
        __syncthreads();
    }
    int excl = sc[tid] - myc;
    cur[tid] = excl;
    int gnode = b * BNODES + tid;
    if (gnode < N) {
        row_ptr[gnode] = eB + excl;
        float d = (float)myc;
        dis[gnode] = d > 0.0f ? rsqrtf(fmaxf(d, 1.0f)) : 0.0f;
    }
    __syncthreads();
    for (int i = tid; i < eN; i += 256) {
        unsigned int v = eL[i];
        int pos = atomicAdd(&cur[v >> 24], 1);
        outL[pos] = v & 0xFFFFFFu;
    }
    __syncthreads();
    for (int i = tid; i < eN; i += 256)
        csr_src[eB + i] = (int)outL[i];
}

// ---------- gemm1 via MFMA bf16: 64 rows/block, 4 waves x (16 rows x 64 cols) ----------
__global__ __launch_bounds__(256) void gemm1_kernel(
        const float* __restrict__ x, const unsigned short* __restrict__ w1t,
        const float* __restrict__ dis, unsigned short* __restrict__ h1b, int N) {
    __shared__ unsigned short xs[64][136];
    __shared__ unsigned short wsb[64][136];
    __shared__ float diss[64];
    int tid = threadIdx.x;
    int w = tid >> 6;
    int lane = tid & 63;
    int row0 = blockIdx.x * 64;

    #pragma unroll
    for (int it = 0; it < 8; it++) {
        int f = it * 256 + tid;
        int r = f >> 5, c = f & 31;
        float4 v = make_float4(0.f, 0.f, 0.f, 0.f);
        if (row0 + r < N) v = ((const float4*)x)[(size_t)(row0 + r) * 32 + c];
        unsigned int p0 = (unsigned int)f2bf(v.x) | ((unsigned int)f2bf(v.y) << 16);
        unsigned int p1 = (unsigned int)f2bf(v.z) | ((unsigned int)f2bf(v.w) << 16);
        *(uint2*)&xs[r][c * 4] = make_uint2(p0, p1);
    }
    #pragma unroll
    for (int it = 0; it < 4; it++) {
        int f = it * 256 + tid;
        int r = f >> 4, c = f & 15;
        *(uint4*)&wsb[r][c * 8] = ((const uint4*)w1t)[f];
    }
    if (tid < 64) diss[tid] = (row0 + tid < N) ? dis[row0 + tid] : 0.f;
    __syncthreads();

    int q = lane >> 4;
    int l15 = lane & 15;
    f32x4 acc[4] = {{0,0,0,0},{0,0,0,0},{0,0,0,0},{0,0,0,0}};
    bf16x8 a[4];
    #pragma unroll
    for (int kk = 0; kk < 4; kk++)
        a[kk] = *(const bf16x8*)&xs[w * 16 + l15][kk * 32 + q * 8];
    #pragma unroll
    for (int kk = 0; kk < 4; kk++) {
        #pragma unroll
        for (int ct = 0; ct < 4; ct++) {
            bf16x8 b = *(const bf16x8*)&wsb[ct * 16 + l15][kk * 32 + q * 8];
            acc[ct] = __builtin_amdgcn_mfma_f32_16x16x32_bf16(a[kk], b, acc[ct], 0, 0, 0);
        }
    }
    __syncthreads();
    #pragma unroll
    for (int ct = 0; ct < 4; ct++) {
        #pragma unroll
        for (int r = 0; r < 4; r++) {
            int m = w * 16 + q * 4 + r;
            xs[m][ct * 16 + l15] = f2bf(acc[ct][r] * diss[m]);
        }
    }
    __syncthreads();
    #pragma unroll
    for (int it = 0; it < 2; it++) {
        int f = it * 256 + tid;
        int r = f >> 3, c = f & 7;
        if (row0 + r < N)
            ((uint4*)&h1b[(size_t)(row0 + r) * HID])[c] = *(const uint4*)&xs[r][c * 8];
    }
}

// ---------- fused layer-1 agg + ReLU + W2 GEMM ----------
// 2 nodes per wave (8 outstanding gathers), branch-free predicated batch-4 per node
__global__ __launch_bounds__(256) void agg1_fused(
        const int* __restrict__ row_ptr, const int* __restrict__ csr_src,
        const unsigned short* __restrict__ h1b, const float* __restrict__ dis,
        const float* __restrict__ b1, const float* __restrict__ W2,
        unsigned short* __restrict__ h2b, int N) {
    __shared__ float W2s[HID][NCLS + 1];
    __shared__ float ts[8][HID];
    int tid = threadIdx.x;
    for (int i = tid; i < HID * NCLS; i += 256) W2s[i >> 4][i & 15] = W2[i];
    __syncthreads();

    int w = tid >> 6;
    int lane = tid & 63;
    int slot = lane >> 4;    // edge slot 0..3
    int p = lane & 15;       // dim-quad: dims p*4..p*4+3
    int nA = blockIdx.x * 8 + w * 2;
    int nB = nA + 1;

    float aA0 = 0.f, aA1 = 0.f, aA2 = 0.f, aA3 = 0.f;
    float aB0 = 0.f, aB1 = 0.f, aB2 = 0.f, aB3 = 0.f;
    float dnA = 0.f, dnB = 0.f;
    int begA = 0, endA = 0, begB = 0, endB = 0;
    if (nA < N) { dnA = dis[nA]; begA = row_ptr[nA]; endA = row_ptr[nA + 1]; }
    if (nB < N) { dnB = dis[nB]; begB = row_ptr[nB]; endB = row_ptr[nB + 1]; }

    int iA = begA + slot;
    int iB = begB + slot;
    while (iA < endA || iB < endB) {
        // clamped index loads: always-valid addresses, all 8 issue up front
        int eAm = max(endA - 1, 0);
        int eBm = max(endB - 1, 0);
        int jA0 = min(iA,      eAm), jA1 = min(iA + 4,  eAm);
        int jA2 = min(iA + 8,  eAm), jA3 = min(iA + 12, eAm);
        int jB0 = min(iB,      eBm), jB1 = min(iB + 4,  eBm);
        int jB2 = min(iB + 8,  eBm), jB3 = min(iB + 12, eBm);
        int sA0 = csr_src[jA0], sA1 = csr_src[jA1], sA2 = csr_src[jA2], sA3 = csr_src[jA3];
        int sB0 = csr_src[jB0], sB1 = csr_src[jB1], sB2 = csr_src[jB2], sB3 = csr_src[jB3];
        uint2 vA0 = *(const uint2*)&h1b[(size_t)sA0 * HID + p * 4];
        uint2 vA1 = *(const uint2*)&h1b[(size_t)sA1 * HID + p * 4];
        uint2 vA2 = *(const uint2*)&h1b[(size_t)sA2 * HID + p * 4];
        uint2 vA3 = *(const uint2*)&h1b[(size_t)sA3 * HID + p * 4];
        uint2 vB0 = *(const uint2*)&h1b[(size_t)sB0 * HID + p * 4];
        uint2 vB1 = *(const uint2*)&h1b[(size_t)sB1 * HID + p * 4];
        uint2 vB2 = *(const uint2*)&h1b[(size_t)sB2 * HID + p * 4];
        uint2 vB3 = *(const uint2*)&h1b[(size_t)sB3 * HID + p * 4];
        float mA0 = (iA      < endA) ? 1.f : 0.f;
        float mA1 = (iA + 4  < endA) ? 1.f : 0.f;
        float mA2 = (iA + 8  < endA) ? 1.f : 0.f;
        float mA3 = (iA + 12 < endA) ? 1.f : 0.f;
        float mB0 = (iB      < endB) ? 1.f : 0.f;
        float mB1 = (iB + 4  < endB) ? 1.f : 0.f;
        float mB2 = (iB + 8  < endB) ? 1.f : 0.f;
        float mB3 = (iB + 12 < endB) ? 1.f : 0.f;
        aA0 = fmaf(mA0, bflo(vA0.x), aA0); aA0 = fmaf(mA1, bflo(vA1.x), aA0);
        aA0 = fmaf(mA2, bflo(vA2.x), aA0); aA0 = fmaf(mA3, bflo(vA3.x), aA0);
        aA1 = fmaf(mA0, bfhi(vA0.x), aA1); aA1 = fmaf(mA1, bfhi(vA1.x), aA1);
        aA1 = fmaf(mA2, bfhi(vA2.x), aA1); aA1 = fmaf(mA3, bfhi(vA3.x), aA1);
        aA2 = fmaf(mA0, bflo(vA0.y), aA2); aA2 = fmaf(mA1, bflo(vA1.y), aA2);
        aA2 = fmaf(mA2, bflo(vA2.y), aA2); aA2 = fmaf(mA3, bflo(vA3.y), aA2);
        aA3 = fmaf(mA0, bfhi(vA0.y), aA3); aA3 = fmaf(mA1, bfhi(vA1.y), aA3);
        aA3 = fmaf(mA2, bfhi(vA2.y), aA3); aA3 = fmaf(mA3, bfhi(vA3.y), aA3);
        aB0 = fmaf(mB0, bflo(vB0.x), aB0); aB0 = fmaf(mB1, bflo(vB1.x), aB0);
        aB0 = fmaf(mB2, bflo(vB2.x), aB0); aB0 = fmaf(mB3, bflo(vB3.x), aB0);
        aB1 = fmaf(mB0, bfhi(vB0.x), aB1); aB1 = fmaf(mB1, bfhi(vB1.x), aB1);
        aB1 = fmaf(mB2, bfhi(vB2.x), aB1); aB1 = fmaf(mB3, bfhi(vB3.x), aB1);
        aB2 = fmaf(mB0, bflo(vB0.y), aB2); aB2 = fmaf(mB1, bflo(vB1.y), aB2);
        aB2 = fmaf(mB2, bflo(vB2.y), aB2); aB2 = fmaf(mB3, bflo(vB3.y), aB2);
        aB3 = fmaf(mB0, bfhi(vB0.y), aB3); aB3 = fmaf(mB1, bfhi(vB1.y), aB3);
        aB3 = fmaf(mB2, bfhi(vB2.y), aB3); aB3 = fmaf(mB3, bfhi(vB3.y), aB3);
        iA += 16;
        iB += 16;
    }

    // reduce across the 4 edge slots (both nodes)
    aA0 += __shfl_xor(aA0, 16, 64); aA0 += __shfl_xor(aA0, 32, 64);
    aA1 += __shfl_xor(aA1, 16, 64); aA1 += __shfl_xor(aA1, 32, 64);
    aA2 += __shfl_xor(aA2, 16, 64); aA2 += __shfl_xor(aA2, 32, 64);
    aA3 += __shfl_xor(aA3, 16, 64); aA3 += __shfl_xor(aA3, 32, 64);
    aB0 += __shfl_xor(aB0, 16, 64); aB0 += __shfl_xor(aB0, 32, 64);
    aB1 += __shfl_xor(aB1, 16, 64); aB1 += __shfl_xor(aB1, 32, 64);
    aB2 += __shfl_xor(aB2, 16, 64); aB2 += __shfl_xor(aB2, 32, 64);
    aB3 += __shfl_xor(aB3, 16, 64); aB3 += __shfl_xor(aB3, 32, 64);

    if (slot == 0) {
        if (nA < N) {
            ts[w * 2][p * 4 + 0] = fmaxf(dnA * aA0 + b1[p * 4 + 0], 0.f);
            ts[w * 2][p * 4 + 1] = fmaxf(dnA * aA1 + b1[p * 4 + 1], 0.f);
            ts[w * 2][p * 4 + 2] = fmaxf(dnA * aA2 + b1[p * 4 + 2], 0.f);
            ts[w * 2][p * 4 + 3] = fmaxf(dnA * aA3 + b1[p * 4 + 3], 0.f);
        }
        if (nB < N) {
            ts[w * 2 + 1][p * 4 + 0] = fmaxf(dnB * aB0 + b1[p * 4 + 0], 0.f);
            ts[w * 2 + 1][p * 4 + 1] = fmaxf(dnB * aB1 + b1[p * 4 + 1], 0.f);
            ts[w * 2 + 1][p * 4 + 2] = fmaxf(dnB * aB2 + b1[p * 4 + 2], 0.f);
            ts[w * 2 + 1][p * 4 + 3] = fmaxf(dnB * aB3 + b1[p * 4 + 3], 0.f);
        }
    }
    // wave-local LDS round-trip (same wave writes+reads; compiler inserts lgkmcnt)
    int q = lane >> 4;
    int c = lane & 15;
    float pA = 0.f, pB = 0.f;
    #pragma unroll
    for (int jj = 0; jj < 16; jj++) {
        int j = q * 16 + jj;
        pA += ts[w * 2][j] * W2s[j][c];
        pB += ts[w * 2 + 1][j] * W2s[j][c];
    }
    pA += __shfl_xor(pA, 16, 64);
    pA += __shfl_xor(pA, 32, 64);
    pB += __shfl_xor(pB, 16, 64);
    pB += __shfl_xor(pB, 32, 64);
    if (q == 0) {
        if (nA < N) h2b[(size_t)nA * NCLS + c] = f2bf(pA * dnA);
        if (nB < N) h2b[(size_t)nB * NCLS + c] = f2bf(pB * dnB);
    }
}

// ---------- fused layer-2 agg + epilogue ----------
__global__ __launch_bounds__(256) void agg2_fused(
        const int* __restrict__ row_ptr, const int* __restrict__ csr_src,
        const unsigned short* __restrict__ h2b, const float* __restrict__ dis,
        const float* __restrict__ b2, float* __restrict__ out, int N) {
    int tid = blockIdx.x * blockDim.x + threadIdx.x;
    int n = tid >> 6;
    int lane = tid & 63;
    if (n >= N) return;
    int slot = lane >> 2;
    int p = lane & 3;

    float a0 = 0.f, a1 = 0.f, a2 = 0.f, a3 = 0.f;
    int beg = row_ptr[n];
    int end = row_ptr[n + 1];
    for (int i = beg + slot; i < end; i += 16) {
        int s = csr_src[i];
        uint2 v = *(const uint2*)&h2b[(size_t)s * NCLS + p * 4];
        a0 += bflo(v.x);
        a1 += bfhi(v.x);
        a2 += bflo(v.y);
        a3 += bfhi(v.y);
    }
    #pragma unroll
    for (int m = 4; m <= 32; m <<= 1) {
        a0 += __shfl_xor(a0, m, 64);
        a1 += __shfl_xor(a1, m, 64);
        a2 += __shfl_xor(a2, m, 64);
        a3 += __shfl_xor(a3, m, 64);
    }
    if (lane < 4) {
        float dn = dis[n];
        float4 o = make_float4(dn * a0 + b2[p * 4 + 0], dn * a1 + b2[p * 4 + 1],
                               dn * a2 + b2[p * 4 + 2], dn * a3 + b2[p * 4 + 3]);
        *(float4*)&out[(size_t)n * NCLS + p * 4] = o;
    }
}

extern "C" void kernel_launch(void* const* d_in, const int* in_sizes, int n_in,
                              void* d_out, int out_size, void* d_ws, size_t ws_size,
                              hipStream_t stream) {
    const float* x   = (const float*)d_in[0];
    const int*   src = (const int*)  d_in[1];
    const int*   dst = (const int*)  d_in[2];
    const float* W1  = (const float*)d_in[3];
    const float* b1  = (const float*)d_in[4];
    const float* W2  = (const float*)d_in[5];
    const float* b2  = (const float*)d_in[6];
    float* out = (float*)d_out;
    int E = in_sizes[1];
    int N = in_sizes[0] / F_IN;
    int NB = (N + BNODES - 1) >> BSHIFT;
    int nchunks = (E + CHUNK - 1) / CHUNK;   // 208 for E=1.7M (col_scan requires <=256)

    char* ws = (char*)d_ws;
    size_t off = 0;
    auto alloc = [&](size_t bytes) { size_t o = off; off = (off + bytes + 255) & ~(size_t)255; return (void*)(ws + o); };
    int*   bucket_count  = (int*)  alloc((size_t)NB * 4);
    int*   bucket_base   = (int*)  alloc((size_t)(NB + 1) * 4);
    int*   blk_hist      = (int*)  alloc((size_t)nchunks * NB * 4);
    int*   row_ptr       = (int*)  alloc((size_t)(N + 1) * 4);
    int*   csr_src       = (int*)  alloc((size_t)E * 4);
    float* dis           = (float*)alloc((size_t)N * 4);
    unsigned short* w1t  = (unsigned short*)alloc((size_t)F_IN * HID * 2);
    unsigned short* h1b  = (unsigned short*)alloc((size_t)N * HID * 2);
    unsigned short* h2b  = (unsigned short*)alloc((size_t)N * NCLS * 2);
    // part[] aliases h1b: dead before gemm1 writes h1b (E*4 = 6.8MB <= N*HID*2 = 12.8MB)
    unsigned int* part   = (unsigned int*)h1b;

    hist_w1t_kernel<<<nchunks + 1, 256, 0, stream>>>(dst, blk_hist, W1, w1t, E, NB, nchunks);
    col_reduce     <<<NB, 256, 0, stream>>>(blk_hist, bucket_count, NB, nchunks);
    scan_small     <<<1, 512, 0, stream>>>(bucket_count, bucket_base, row_ptr, NB, N, E);
    col_scan       <<<NB, 256, 0, stream>>>(blk_hist, bucket_base, NB, nchunks);
    scatter_kernel <<<nchunks, 256, 0, stream>>>(src, dst, blk_hist, part, E, NB);
    csr_build      <<<NB, 256, 0, stream>>>(part, bucket_base, csr_src, row_ptr, dis, N);
    gemm1_kernel   <<<(N + 63) / 64, 256, 0, stream>>>(x, w1t, dis, h1b, N);
    agg1_fused     <<<(N + 7) / 8, 256, 0, stream>>>(row_ptr, csr_src, h1b, dis, b1, W2, h2b, N);
    agg2_fused     <<<(N + 3) / 4, 256, 0, stream>>>(row_ptr, csr_src, h2b, dis, b2, out, N);
}